// Round 5
// baseline (451.166 us; speedup 1.0000x reference)
//
#include <hip/hip_runtime.h>
#include <hip/hip_bf16.h>

// Fused MHA: qkv = x@Wqkv+b ; attention ; out = attn@Wout+b
// B=4 S=2048 D=1024 H=16 hd=64. bf16 MFMA, f32 accum/softmax.
// attn: 32x32x16 MFMA, LDS-free; permlane32_swap for all cross-half exchange;
// XCD-aware head swizzle so each head's K/V stays in one XCD's L2.

#define S_ 2048
#define DM 1024
#define NH 16
#define HD 64

typedef unsigned short u16;
typedef unsigned int u32;
typedef __attribute__((ext_vector_type(8))) short short8;
typedef __attribute__((ext_vector_type(4))) float f32x4;
typedef __attribute__((ext_vector_type(16))) float f32x16;
typedef __attribute__((ext_vector_type(4))) u32 u32x4;

extern "C" __device__ float __ocml_native_exp2_f32(float);

#define MFMA(a, b, c) __builtin_amdgcn_mfma_f32_16x16x32_bf16((a), (b), (c), 0, 0, 0)
#define MFMA32(a, b, c) __builtin_amdgcn_mfma_f32_32x32x16_bf16((a), (b), (c), 0, 0, 0)
#define C1 0.18033688f   // 0.125 * log2(e)

static __device__ __forceinline__ u16 f2bf(float f) {
  return __builtin_bit_cast(u16, __float2bfloat16(f));
}
static __device__ __forceinline__ u32 pack2bf(float a, float b) {
  return (u32)f2bf(a) | ((u32)f2bf(b) << 16);
}
static __device__ __forceinline__ short8 ld8(const u16* p) {
  return *reinterpret_cast<const short8*>(p);
}
static __device__ __forceinline__ void gl_lds16(const u16* g, u16* l) {
  __builtin_amdgcn_global_load_lds((__attribute__((address_space(1))) void*)(u16*)g,
                                   (__attribute__((address_space(3))) void*)l, 16, 0, 0);
}
// v_permlane32_swap_b32: a'={a.lo, b.lo-from-partner-view}:
//   a'[l<32]=a[l], a'[l>=32]=b[l-32];  b'[l<32]=a[l+32], b'[l>=32]=b[l]
static __device__ __forceinline__ void plswap(u32& a, u32& b) {
#if __has_builtin(__builtin_amdgcn_permlane32_swap)
  typedef __attribute__((ext_vector_type(2))) unsigned int u32x2_t;
  u32x2_t r = __builtin_amdgcn_permlane32_swap(a, b, false, false);
  a = r.x; b = r.y;
#else
  asm("v_permlane32_swap_b32 %0, %1" : "+v"(a), "+v"(b));
#endif
}
static __device__ __forceinline__ float xhalf_max(float x) {
  u32 a = __builtin_bit_cast(u32, x), b = a;
  plswap(a, b);
  return fmaxf(__builtin_bit_cast(float, a), __builtin_bit_cast(float, b));
}
static __device__ __forceinline__ float xhalf_sum(float x) {
  u32 a = __builtin_bit_cast(u32, x), b = a;
  plswap(a, b);
  return __builtin_bit_cast(float, a) + __builtin_bit_cast(float, b);
}

// ---------------- cast x (f32 -> bf16) ----------------
__global__ __launch_bounds__(256) void cast_x_kernel(const float4* __restrict__ in,
                                                     uint2* __restrict__ out, int n4) {
  int i = blockIdx.x * 256 + threadIdx.x;
  if (i >= n4) return;
  float4 v = in[i];
  uint2 o;
  o.x = pack2bf(v.x, v.y);
  o.y = pack2bf(v.z, v.w);
  out[i] = o;
}

// ---- tiled transpose+cast: in [1024][N] f32 -> out [N][1024] bf16 ----
__global__ __launch_bounds__(256) void transpose_cast_kernel(const float* __restrict__ in,
                                                             u16* __restrict__ out, int N) {
  __shared__ float tile[32][33];
  const int bk = blockIdx.y * 32, bn = blockIdx.x * 32;
  const int r = threadIdx.x >> 3, c4 = (threadIdx.x & 7) * 4;
  float4 v = *reinterpret_cast<const float4*>(&in[(size_t)(bk + r) * N + bn + c4]);
  tile[r][c4 + 0] = v.x; tile[r][c4 + 1] = v.y;
  tile[r][c4 + 2] = v.z; tile[r][c4 + 3] = v.w;
  __syncthreads();
  uint2 o;
  o.x = pack2bf(tile[c4 + 0][r], tile[c4 + 1][r]);
  o.y = pack2bf(tile[c4 + 2][r], tile[c4 + 3][r]);
  *reinterpret_cast<uint2*>(&out[(size_t)(bn + r) * 1024 + bk + c4]) = o;
}

// ---------------- GEMM: C[M,N] = A[M,1024] @ BT[N,1024]^T + bias ----------------
__global__ __launch_bounds__(256) void gemm_bt_kernel(
    const u16* __restrict__ A, const u16* __restrict__ BT, const float* __restrict__ bias,
    int mode, u16* __restrict__ Qb, u16* __restrict__ Kb, u16* __restrict__ VT,
    float* __restrict__ outF) {
  __shared__ __align__(16) u16 As[128 * 32];
  __shared__ __align__(16) u16 Bs[128 * 32];
  const int tid = threadIdx.x, lane = tid & 63, wid = tid >> 6;
  const int m0 = blockIdx.y * 128, n0 = blockIdx.x * 128;
  const int wm = (wid >> 1) * 64, wn = (wid & 1) * 64;
  const int g = lane >> 4, lr = lane & 15;
  const int srow16 = lane >> 2, scol8 = (lane & 3) * 8;
  f32x4 acc[4][4] = {};

  for (int k0 = 0; k0 < 1024; k0 += 32) {
#pragma unroll
    for (int i = 0; i < 2; ++i) {
      int sA = wid + i * 4;
      gl_lds16(&A[(size_t)(m0 + sA * 16 + srow16) * 1024 + k0 + scol8], &As[sA * 512]);
      gl_lds16(&BT[(size_t)(n0 + sA * 16 + srow16) * 1024 + k0 + scol8], &Bs[sA * 512]);
    }
    __syncthreads();
    short8 af[4], bfr[4];
#pragma unroll
    for (int mb = 0; mb < 4; ++mb)
      af[mb] = ld8(&As[(wm + mb * 16 + lr) * 32 + g * 8]);
#pragma unroll
    for (int nb = 0; nb < 4; ++nb)
      bfr[nb] = ld8(&Bs[(wn + nb * 16 + lr) * 32 + g * 8]);
#pragma unroll
    for (int mb = 0; mb < 4; ++mb)
#pragma unroll
      for (int nb = 0; nb < 4; ++nb)
        acc[mb][nb] = MFMA(af[mb], bfr[nb], acc[mb][nb]);
    __syncthreads();
  }

  if (mode == 0) {
#pragma unroll
    for (int nb = 0; nb < 4; ++nb) {
      int col = n0 + wn + nb * 16 + lr;          // 0..3071
      int hh = col / 192;
      int c = col - hh * 192;
      int t = c >> 6, d = c & 63;
      float bv = bias[col];
#pragma unroll
      for (int mb = 0; mb < 4; ++mb)
#pragma unroll
        for (int r = 0; r < 4; ++r) {
          int rowg = m0 + wm + mb * 16 + g * 4 + r;
          int b = rowg >> 11, s = rowg & 2047;
          u16 v = f2bf(acc[mb][nb][r] + bv);
          int head = b * NH + hh;
          if (t == 0)      Qb[(head * S_ + s) * HD + d] = v;
          else if (t == 1) Kb[(head * S_ + s) * HD + d] = v;
          else             VT[((size_t)head * HD + d) * S_ + s] = v;
        }
    }
  } else {
#pragma unroll
    for (int nb = 0; nb < 4; ++nb) {
      int col = n0 + wn + nb * 16 + lr;
      float bv = bias[col];
#pragma unroll
      for (int mb = 0; mb < 4; ++mb)
#pragma unroll
        for (int r = 0; r < 4; ++r) {
          int rowg = m0 + wm + mb * 16 + g * 4 + r;
          outF[(size_t)rowg * DM + col] = acc[mb][nb][r] + bv;
        }
    }
  }
}

// ---------------- flash attention, 32x32x16, LDS-free ----------------
// Wave: 32 q-rows. S^T = K.Q^T -> lane holds 32 scores of ONE q (col=lane&31).
// C-layout: row k_local = (r&3)+8*(r>>2)+4*hi. P redistribution for PV via
// permlane32_swap (VALU). No LDS, no DS ops, no barriers.
// Block swizzle: head = ((i>>7)<<3)|(i&7) -> all 16 q-blocks of a head on one
// XCD (round-robin i%8 heuristic) so K/V (512KB) stays L2-resident.
__global__ __launch_bounds__(256, 2) void attn_kernel(const u16* __restrict__ Qb,
                                                      const u16* __restrict__ Kb,
                                                      const u16* __restrict__ VT,
                                                      u16* __restrict__ attn_out) {
  const int lane = threadIdx.x & 63, wid = threadIdx.x >> 6;
  const int i = blockIdx.x;
  const int head = ((i >> 7) << 3) | (i & 7);
  const int qb = (i >> 3) & 15;
  const int l31 = lane & 31, hi = lane >> 5;
  const int q = qb * 128 + wid * 32 + l31;
  const u16* Qh = Qb + (size_t)head * S_ * HD;
  const u16* Kh = Kb + (size_t)head * S_ * HD;
  const u16* Vh = VT + (size_t)head * HD * S_;

  short8 qf[4];
#pragma unroll
  for (int dt = 0; dt < 4; ++dt)
    qf[dt] = ld8(&Qh[q * HD + dt * 16 + hi * 8]);

  short8 kf[2][4];
#pragma unroll
  for (int kt = 0; kt < 2; ++kt)
#pragma unroll
    for (int dt = 0; dt < 4; ++dt)
      kf[kt][dt] = ld8(&Kh[(kt * 32 + l31) * HD + dt * 16 + hi * 8]);

  f32x16 o0 = {}, o1 = {};
  float m_run = -1e30f, l_run = 0.f;

#pragma unroll 1
  for (int kv0 = 0; kv0 < S_; kv0 += 64) {
    // V loads for this tile (consumed after softmax)
    short8 vf0[4], vf1[4];
#pragma unroll
    for (int kc = 0; kc < 4; ++kc) {
      vf0[kc] = ld8(&Vh[(size_t)l31 * S_ + kv0 + kc * 16 + hi * 8]);
      vf1[kc] = ld8(&Vh[(size_t)(32 + l31) * S_ + kv0 + kc * 16 + hi * 8]);
    }
    // S^T = K . Q^T
    f32x16 s0 = {}, s1 = {};
#pragma unroll
    for (int dt = 0; dt < 4; ++dt) s0 = MFMA32(kf[0][dt], qf[dt], s0);
#pragma unroll
    for (int dt = 0; dt < 4; ++dt) s1 = MFMA32(kf[1][dt], qf[dt], s1);
    // prefetch next K tile (consumed next iteration)
    int kvn = (kv0 + 64) & (S_ - 1);
#pragma unroll
    for (int kt = 0; kt < 2; ++kt)
#pragma unroll
      for (int dt = 0; dt < 4; ++dt)
        kf[kt][dt] = ld8(&Kh[(kvn + kt * 32 + l31) * HD + dt * 16 + hi * 8]);
    // row max: in-lane tree over 32 + one cross-half exchange (permlane)
    float mx[8];
#pragma unroll
    for (int r = 0; r < 8; ++r)
      mx[r] = fmaxf(fmaxf(s0[r], s0[r + 8]), fmaxf(s1[r], s1[r + 8]));
    float m01 = fmaxf(fmaxf(mx[0], mx[1]), fmaxf(mx[2], mx[3]));
    float m23 = fmaxf(fmaxf(mx[4], mx[5]), fmaxf(mx[6], mx[7]));
    float smax = xhalf_max(fmaxf(m01, m23));
    bool keep = __all(smax <= m_run + 40.0f);     // T13 defer-max
    float m_new = keep ? m_run : fmaxf(m_run, smax);
    float base = m_new * C1;
    float p0 = 0.f, p1 = 0.f, p2 = 0.f, p3 = 0.f;
#pragma unroll
    for (int m = 0; m < 4; ++m) {
      s0[m * 4 + 0] = __ocml_native_exp2_f32(fmaf(s0[m * 4 + 0], C1, -base));
      s0[m * 4 + 1] = __ocml_native_exp2_f32(fmaf(s0[m * 4 + 1], C1, -base));
      s0[m * 4 + 2] = __ocml_native_exp2_f32(fmaf(s0[m * 4 + 2], C1, -base));
      s0[m * 4 + 3] = __ocml_native_exp2_f32(fmaf(s0[m * 4 + 3], C1, -base));
      s1[m * 4 + 0] = __ocml_native_exp2_f32(fmaf(s1[m * 4 + 0], C1, -base));
      s1[m * 4 + 1] = __ocml_native_exp2_f32(fmaf(s1[m * 4 + 1], C1, -base));
      s1[m * 4 + 2] = __ocml_native_exp2_f32(fmaf(s1[m * 4 + 2], C1, -base));
      s1[m * 4 + 3] = __ocml_native_exp2_f32(fmaf(s1[m * 4 + 3], C1, -base));
      p0 += s0[m * 4 + 0] + s1[m * 4 + 0];
      p1 += s0[m * 4 + 1] + s1[m * 4 + 1];
      p2 += s0[m * 4 + 2] + s1[m * 4 + 2];
      p3 += s0[m * 4 + 3] + s1[m * 4 + 3];
    }
    float psum = xhalf_sum((p0 + p1) + (p2 + p3));
    if (keep) {
      l_run += psum;
    } else {
      float corr = __ocml_native_exp2_f32((m_run - m_new) * C1);
      l_run = l_run * corr + psum;
      m_run = m_new;
#pragma unroll
      for (int r = 0; r < 16; ++r) { o0[r] *= corr; o1[r] *= corr; }
    }
    // pack P pairs: word index m' in [0,8): k = 8*m' + 4*hi + {0,1} (wA), {2,3} (wB)
    u32 wA[8], wB[8];
#pragma unroll
    for (int m = 0; m < 4; ++m) {
      wA[m] = pack2bf(s0[m * 4 + 0], s0[m * 4 + 1]);
      wB[m] = pack2bf(s0[m * 4 + 2], s0[m * 4 + 3]);
      wA[4 + m] = pack2bf(s1[m * 4 + 0], s1[m * 4 + 1]);
      wB[4 + m] = pack2bf(s1[m * 4 + 2], s1[m * 4 + 3]);
    }
    // PV B-frag per 16-k chunk: one permlane pair per (A,B) stream
#pragma unroll
    for (int kc = 0; kc < 4; ++kc) {
      u32 a0 = wA[2 * kc], a1 = wA[2 * kc + 1];
      u32 b0 = wB[2 * kc], b1 = wB[2 * kc + 1];
      plswap(a0, a1);   // a0 -> bw.x, a1 -> bw.z (both halves)
      plswap(b0, b1);   // b0 -> bw.y, b1 -> bw.w
      u32x4 bw;
      bw.x = a0; bw.y = b0; bw.z = a1; bw.w = b1;
      short8 pf = __builtin_bit_cast(short8, bw);
      o0 = MFMA32(vf0[kc], pf, o0);
      o1 = MFMA32(vf1[kc], pf, o1);
    }
  }

  const int b = head >> 4, h = head & 15;
  float inv = 1.f / l_run;
  u16* dst = attn_out + (size_t)(b * S_ + q) * DM + h * HD;
#pragma unroll
  for (int rg = 0; rg < 4; ++rg) {
    uint2 k0, k1;
    k0.x = pack2bf(o0[rg * 4 + 0] * inv, o0[rg * 4 + 1] * inv);
    k0.y = pack2bf(o0[rg * 4 + 2] * inv, o0[rg * 4 + 3] * inv);
    *reinterpret_cast<uint2*>(dst + rg * 8 + hi * 4) = k0;
    k1.x = pack2bf(o1[rg * 4 + 0] * inv, o1[rg * 4 + 1] * inv);
    k1.y = pack2bf(o1[rg * 4 + 2] * inv, o1[rg * 4 + 3] * inv);
    *reinterpret_cast<uint2*>(dst + 32 + rg * 8 + hi * 4) = k1;
  }
}

extern "C" void kernel_launch(void* const* d_in, const int* in_sizes, int n_in,
                              void* d_out, int out_size, void* d_ws, size_t ws_size,
                              hipStream_t stream) {
  const float* x    = (const float*)d_in[0];
  const float* Wqkv = (const float*)d_in[1];
  const float* bqkv = (const float*)d_in[2];
  const float* Wout = (const float*)d_in[3];
  const float* bout = (const float*)d_in[4];
  float* out = (float*)d_out;

  char* ws = (char*)d_ws;
  u16* xb      = (u16*)(ws);                  // 8192*1024 bf16
  u16* WqkvT   = (u16*)(ws + 16777216);       // 3072*1024
  u16* WoutT   = (u16*)(ws + 23068672);       // 1024*1024
  u16* Qb      = (u16*)(ws + 25165824);       // 64*2048*64
  u16* Kb      = (u16*)(ws + 41943040);
  u16* VT      = (u16*)(ws + 58720256);
  u16* attn_out = xb;                          // reuse after gemm1 consumed x

  cast_x_kernel<<<8192, 256, 0, stream>>>((const float4*)x, (uint2*)xb, 8192 * 1024 / 4);
  transpose_cast_kernel<<<dim3(96, 32), 256, 0, stream>>>(Wqkv, WqkvT, 3072);
  transpose_cast_kernel<<<dim3(32, 32), 256, 0, stream>>>(Wout, WoutT, 1024);

  gemm_bt_kernel<<<dim3(24, 64), 256, 0, stream>>>(xb, WqkvT, bqkv, 0, Qb, Kb, VT, nullptr);
  attn_kernel<<<dim3(1024), 256, 0, stream>>>(Qb, Kb, VT, attn_out);
  gemm_bt_kernel<<<dim3(8, 64), 256, 0, stream>>>(attn_out, WoutT, bout, 1, nullptr, nullptr,
                                                  nullptr, out);
}